// Round 12
// baseline (586.159 us; speedup 1.0000x reference)
//
#include <hip/hip_runtime.h>

// Chamfer distance, B=8, N=M=8192, 3-D fp32 points — LDS-tiled MFMA.
// d2 = xx + yy - 2x.y inside mfma_f32_32x32x16_bf16 via split-precision limbs
// packed along K (13/16 slots; absmax 0.0 in R4-R11):
//   A row (query q):  [(-2q)h*3, (-2q)l*3, (-2q)h*3, qqh, qql, 1, 1, 0,0,0]
//   B col (target t): [ th*3,     th*3,     tl*3,    1, 1, tth, ttl, 0,0,0]
// R12: 1024x1024 block tiles, A AND B fragments staged in LDS (plane-split:
// lo-halves then hi-halves -> contiguous 16B ds_read_b128). Cuts global
// fragment traffic 512MB -> 64MB (R7-R11 were re-read-bound: perf tracked
// MFMA-per-load across rounds). Cross-block row-merge via global atomicMin;
// fin uses the R3-verified counter pattern.

#define BB 8
#define NN 8192
#define NPTS (BB*NN)  // 65536
#define BLK 256
#define GRID 1024     // dir(2) x b(8) x rc(8) x cc(8)

typedef __attribute__((ext_vector_type(8))) short bf16x8;
typedef __attribute__((ext_vector_type(16))) float f32x16;

__device__ __forceinline__ unsigned f2mono(float f) {
    unsigned u = __float_as_uint(f);
    return u ^ ((unsigned)((int)u >> 31) | 0x80000000u);
}
__device__ __forceinline__ float mono2f(unsigned m) {
    unsigned u = ((int)m >= 0) ? ~m : (m ^ 0x80000000u);
    return __uint_as_float(u);
}
__device__ __forceinline__ unsigned bfh(float v) {   // fp32 -> bf16 RNE
    unsigned u = __float_as_uint(v);
    u += 0x7FFFu + ((u >> 16) & 1u);
    return u >> 16;
}
__device__ __forceinline__ float bff(unsigned h) {
    return __uint_as_float(h << 16);
}
__device__ __forceinline__ unsigned pk(unsigned lo, unsigned hi) {
    return (lo & 0xFFFFu) | (hi << 16);
}
__device__ __forceinline__ bf16x8 cvt(uint4 v) { return __builtin_bit_cast(bf16x8, v); }
__device__ __forceinline__ f32x16 vmin3(f32x16 a, f32x16 b, f32x16 c) {
    f32x16 r;
#pragma unroll
    for (int i = 0; i < 16; ++i) r[i] = fminf(fminf(a[i], b[i]), c[i]);
    return r;
}

// grid 512, block 256: one thread per point (x: [0,NPTS), y: [NPTS,2*NPTS)).
// Writes plane-split fragment arrays; inits mind/bsums/counter.
__global__ void prep_kernel(const float* __restrict__ x, const float* __restrict__ y,
                            uint4* __restrict__ aLo, uint4* __restrict__ aHi,
                            uint4* __restrict__ bLo, uint4* __restrict__ bHi,
                            unsigned* __restrict__ mind, float* __restrict__ bsums,
                            unsigned* __restrict__ counter) {
    int i = blockIdx.x * BLK + threadIdx.x;   // 0 .. 2*NPTS-1
    if (i == 0) *counter = 0;
    if (i < 16) bsums[i] = 0.f;
    mind[i] = 0xFFFFFFFFu;
    const float* src = (i < NPTS) ? x : y;
    int j = (i < NPTS) ? i : i - NPTS;
    float c0 = src[3*j], c1 = src[3*j+1], c2 = src[3*j+2];
    float s2 = c0*c0 + c1*c1 + c2*c2;
    unsigned sh = bfh(s2), sl = bfh(s2 - bff(sh));
    float a0 = -2.f*c0, a1 = -2.f*c1, a2 = -2.f*c2;
    unsigned ah0 = bfh(a0), ah1 = bfh(a1), ah2 = bfh(a2);
    unsigned al0 = bfh(a0 - bff(ah0)), al1 = bfh(a1 - bff(ah1)), al2 = bfh(a2 - bff(ah2));
    unsigned bh0 = bfh(c0), bh1 = bfh(c1), bh2 = bfh(c2);
    unsigned bl0 = bfh(c0 - bff(bh0)), bl1 = bfh(c1 - bff(bh1)), bl2 = bfh(c2 - bff(bh2));
    const unsigned one = 0x3F80u;
    aLo[i] = make_uint4(pk(ah0,ah1), pk(ah2,al0), pk(al1,al2), pk(ah0,ah1));
    aHi[i] = make_uint4(pk(ah2,sh),  pk(sl,one),  pk(one,0u),  0u);
    bLo[i] = make_uint4(pk(bh0,bh1), pk(bh2,bh0), pk(bh1,bh2), pk(bl0,bl1));
    bHi[i] = make_uint4(pk(bl2,one), pk(one,sh),  pk(sl,0u),   0u);
}

// grid: 1024 = (dir<<9)|(b<<6)|(rc<<3)|cc ; block 256
__global__ __launch_bounds__(BLK, 2) void
main_kernel(const uint4* __restrict__ aLo, const uint4* __restrict__ aHi,
            const uint4* __restrict__ bLo, const uint4* __restrict__ bHi,
            unsigned* __restrict__ mind) {
    __shared__ uint4 sA[2048];        // [hb*1024 + row] 32 KB
    __shared__ uint4 sB[2048];        // [hb*1024 + col] 32 KB
    __shared__ unsigned colmin[1024]; // 4 KB
    const int bi  = blockIdx.x;
    const int dir = bi >> 9;
    const int b   = (bi >> 6) & 7;
    const int rc  = (bi >> 3) & 7;
    const int cc  = bi & 7;
    const int aoff = (dir ? NPTS : 0) + b * NN + rc * 1024;  // A rows: dir? y : x
    const int boff = (dir ? 0 : NPTS) + b * NN + cc * 1024;  // B cols: opposite
    const int tid = threadIdx.x;
    const int lane = tid & 63, w = tid >> 6;
    const int m = lane & 31;
    const int hb = lane >> 5;

    // stage fragment planes + init colmin
#pragma unroll
    for (int k = 0; k < 4; ++k) {
        int idx = k * BLK + tid;
        sA[idx]        = aLo[aoff + idx];
        sA[1024 + idx] = aHi[aoff + idx];
        sB[idx]        = bLo[boff + idx];
        sB[1024 + idx] = bHi[boff + idx];
        colmin[idx] = 0xFFFFFFFFu;
    }
    __syncthreads();

    f32x16 zro;
#pragma unroll
    for (int i = 0; i < 16; ++i) zro[i] = 0.f;
    const int abase = hb * 1024 + w * 256;
    const int bbase = hb * 1024;

#pragma unroll 1
    for (int ctg = 0; ctg < 8; ++ctg) {
        bf16x8 bf[4];
#pragma unroll
        for (int ct = 0; ct < 4; ++ct)
            bf[ct] = cvt(sB[bbase + ctg * 128 + ct * 32 + m]);
        f32x16 vm[4];
#pragma unroll
        for (int ct = 0; ct < 4; ++ct) vm[ct] = zro + 3.4e38f;

#pragma unroll
        for (int rp = 0; rp < 4; ++rp) {
            bf16x8 afA = cvt(sA[abase + rp * 64 + m]);
            bf16x8 afB = cvt(sA[abase + rp * 64 + 32 + m]);
#pragma unroll
            for (int c2 = 0; c2 < 4; c2 += 2) {
                // 4 MFMAs in flight, min3 pair-merge
                f32x16 a00 = __builtin_amdgcn_mfma_f32_32x32x16_bf16(afA, bf[c2],   zro, 0, 0, 0);
                f32x16 a01 = __builtin_amdgcn_mfma_f32_32x32x16_bf16(afB, bf[c2],   zro, 0, 0, 0);
                f32x16 a10 = __builtin_amdgcn_mfma_f32_32x32x16_bf16(afA, bf[c2+1], zro, 0, 0, 0);
                f32x16 a11 = __builtin_amdgcn_mfma_f32_32x32x16_bf16(afB, bf[c2+1], zro, 0, 0, 0);
                vm[c2]   = vmin3(a00, a01, vm[c2]);     // 16 v_min3_f32
                vm[c2+1] = vmin3(a10, a11, vm[c2+1]);
            }
        }

        // reduce each col-tile's minvec, merge K-halves, combine across waves
#pragma unroll
        for (int ct = 0; ct < 4; ++ct) {
            f32x16 v = vm[ct];
            float p0 = fminf(fminf(v[0], v[1]), fminf(v[2], v[3]));
            float p1 = fminf(fminf(v[4], v[5]), fminf(v[6], v[7]));
            float p2 = fminf(fminf(v[8], v[9]), fminf(v[10], v[11]));
            float p3 = fminf(fminf(v[12], v[13]), fminf(v[14], v[15]));
            float p = fminf(fminf(p0, p1), fminf(p2, p3));
            p = fminf(p, __shfl_xor(p, 32, 64));
            if (hb == 0) atomicMin(&colmin[ctg * 128 + ct * 32 + m], f2mono(p));
        }
    }
    __syncthreads();

    // block-final partial mins for 1024 cols (over this block's 1024 rows)
    unsigned* md = mind + dir * NPTS + b * NN + cc * 1024;
#pragma unroll
    for (int k = 0; k < 4; ++k) {
        int ci = k * BLK + tid;
        atomicMin(&md[ci], colmin[ci]);
    }
}

// grid: 64 blocks = 16 (dir,b) groups x 4 slices; block BLK. Counter-fused final.
__global__ void fin_kernel(const unsigned* __restrict__ mind,
                           float* __restrict__ bsums, unsigned* __restrict__ counter,
                           float* __restrict__ out) {
    __shared__ float red[BLK / 64];
    const int grp = blockIdx.x >> 2;   // dir*8+b ; mind offset = grp*NN
    const int sl  = blockIdx.x & 3;
    const int t = threadIdx.x;
    const unsigned* md = mind + grp * NN;
    float s = 0.f;
#pragma unroll
    for (int k = 0; k < NN / 4 / BLK; ++k) {   // 8 iters
        int i = sl * (NN / 4) + t + k * BLK;
        s += sqrtf(fmaxf(mono2f(md[i]), 0.f) + 1e-10f);
    }
    for (int off = 32; off; off >>= 1) s += __shfl_down(s, off, 64);
    if ((t & 63) == 0) red[t >> 6] = s;
    __syncthreads();
    if (t == 0) {
        float tot = 0.f;
        for (int ww = 0; ww < BLK / 64; ++ww) tot += red[ww];
        atomicAdd(&bsums[grp], tot);
        __threadfence();
        unsigned old = atomicAdd(counter, 1u);
        if (old == 63u) {
            float acc = 0.f;
            for (int bb = 0; bb < BB; ++bb) {
                float s0 = atomicAdd(&bsums[bb], 0.f);       // coherent read
                float s1 = atomicAdd(&bsums[BB + bb], 0.f);
                acc += fmaxf(s0, s1);
            }
            out[0] = acc * (1.0f / (float)NN);
        }
    }
}

extern "C" void kernel_launch(void* const* d_in, const int* in_sizes, int n_in,
                              void* d_out, int out_size, void* d_ws, size_t ws_size,
                              hipStream_t stream) {
    const float* x = (const float*)d_in[0];
    const float* y = (const float*)d_in[1];
    float* out = (float*)d_out;

    char* ws = (char*)d_ws;
    uint4* aLo = (uint4*)ws;                     // 2*NPTS uint4 = 2 MB each
    uint4* aHi = aLo + 2 * NPTS;
    uint4* bLo = aHi + 2 * NPTS;
    uint4* bHi = bLo + 2 * NPTS;
    unsigned* mind = (unsigned*)(bHi + 2 * NPTS);   // 2*NPTS uints = 512 KB
    float* bsums = (float*)(mind + 2 * NPTS);       // 16 floats
    unsigned* counter = (unsigned*)(bsums + 16);    // 1 uint

    prep_kernel<<<(2 * NPTS) / BLK, BLK, 0, stream>>>(x, y, aLo, aHi, bLo, bHi,
                                                      mind, bsums, counter);
    main_kernel<<<GRID, BLK, 0, stream>>>(aLo, aHi, bLo, bHi, mind);
    fin_kernel<<<64, BLK, 0, stream>>>(mind, bsums, counter, out);
}